// Round 13
// baseline (206.717 us; speedup 1.0000x reference)
//
#include <hip/hip_runtime.h>

#define NN 4
#define CC 20
#define HH 64
#define WW 2048
#define CG 4           // channel groups
#define CPG (CC / CG)  // 5 channels per group
#define PX 4           // pixels per thread

// R11 (3rd submission — two prior runs died at container acquisition,
// hypothesis still untested; source audited clean: no OOB, no capture
// violations, reconvergent branches only): R0 proven shape (dy-branch
// fence, (256,4), 3D grid, VGPR=64) with ONE change: each aligned 16B
// chunk is loaded by ONE thread and shared to neighbors via
// __shfl_up/down (thread t's chunk at p0 IS t+1's left chunk and t-1's
// right chunk). Wave-edge lanes 0/63 fix up with one combined
// 2-active-lane load per array; clamps (c0/c2) only ever trigger at
// lanes 0/63, so all shfl'd data is exact.
// VMEM/row 27 -> 18 (9 full + 9 two-lane); TA-cycles ~ -55%; L1 bytes
// -60%; +72 cross-lane ops/row on the idle LDS pipe. Register footprint
// unchanged (same window arrays, different fill).
// Theory under test: kernel is TA/VMEM-issue-bound (fits R0 and R4 data).
// Tripwire: WRITE_SIZE must stay 40960 KB, VGPR <= ~72.

__device__ __forceinline__ float4 shflup4(float4 v) {
    return make_float4(__shfl_up(v.x, 1), __shfl_up(v.y, 1),
                       __shfl_up(v.z, 1), __shfl_up(v.w, 1));
}
__device__ __forceinline__ float4 shfldn4(float4 v) {
    return make_float4(__shfl_down(v.x, 1), __shfl_down(v.y, 1),
                       __shfl_down(v.z, 1), __shfl_down(v.w, 1));
}

__global__ __launch_bounds__(256, 4) void lc_xyz_kernel(
    const float* __restrict__ xyz,
    const float* __restrict__ softmax,
    const int* __restrict__ mask,
    float* __restrict__ out)
{
    const int t  = blockIdx.x * blockDim.x + threadIdx.x;  // pixel-quad index in row
    const int h  = blockIdx.y;
    const int nz = blockIdx.z;
    const int n  = nz >> 2;
    const int cg = nz & 3;
    const int hw = HH * WW;
    const int p0 = t * PX;

    const int  lane = (int)threadIdx.x & 63;
    const bool eL   = (lane == 0);
    const bool eR   = (lane == 63);

    const float* xb  = xyz     + (size_t)n * 3  * hw;
    const float* smb = softmax + (size_t)n * CC * hw + (size_t)(cg * CPG) * hw;
    const int*   mb  = mask    + (size_t)n * hw;

    const int ctr = h * WW + p0;
    const float4 cxv = *(const float4*)(xb + 0 * hw + ctr);
    const float4 cyv = *(const float4*)(xb + 1 * hw + ctr);
    const float4 czv = *(const float4*)(xb + 2 * hw + ctr);
    const float cx[PX] = {cxv.x, cxv.y, cxv.z, cxv.w};
    const float cy[PX] = {cyv.x, cyv.y, cyv.z, cyv.w};
    const float cz[PX] = {czv.x, czv.y, czv.z, czv.w};

    float acc[CPG][PX];
#pragma unroll
    for (int c = 0; c < CPG; ++c)
#pragma unroll
        for (int i = 0; i < PX; ++i) acc[c][i] = 0.f;

    // Window indices j=0..11 map to w = p0-4+j; taps use j = i+dx+2 in [2,9].
    // Own chunk at c1=p0 (aligned, in-bounds). Neighbor chunks via shfl.
    // c0/c2 clamps trigger ONLY at lanes 0/63, which use the edge load.
    int c0 = p0 - 4; if (c0 < 0) c0 = 0;
    const int c1 = p0;
    int c2 = p0 + 4; if (c2 > WW - 4) c2 = WW - 4;
    const int ce = eR ? c2 : c0;          // edge-lane fixup chunk address

    float vf[12];
#pragma unroll
    for (int j = 2; j <= 9; ++j)
        vf[j] = ((unsigned)(p0 - 4 + j) < (unsigned)WW) ? 1.f : 0.f;

#pragma unroll
    for (int dy = -2; dy <= 2; ++dy) {
        const int row = h + dy;
        if ((unsigned)row >= (unsigned)HH) continue;   // wave-uniform
        const int rb = row * WW;

        // Own aligned chunks: 1 int4 + 3 float4 (full-wave).
        const int4   m1i = *(const int4*)(mb + rb + c1);
        const float4 x1 = *(const float4*)(xb + 0 * hw + rb + c1);
        const float4 y1 = *(const float4*)(xb + 1 * hw + rb + c1);
        const float4 z1 = *(const float4*)(xb + 2 * hw + rb + c1);
        const float4 m1 = make_float4((float)m1i.x, (float)m1i.y,
                                      (float)m1i.z, (float)m1i.w);

        // Neighbor chunks via cross-lane (exact for non-edge lanes).
        float4 x0 = shflup4(x1), x2 = shfldn4(x1);
        float4 y0 = shflup4(y1), y2 = shfldn4(y1);
        float4 z0 = shflup4(z1), z2 = shfldn4(z1);
        float4 m0 = shflup4(m1), m2 = shfldn4(m1);

        // Wave-edge fixup: one combined load (2 active lanes) per array.
        if (eL | eR) {
            const int4   mei = *(const int4*)(mb + rb + ce);
            const float4 xe = *(const float4*)(xb + 0 * hw + rb + ce);
            const float4 ye = *(const float4*)(xb + 1 * hw + rb + ce);
            const float4 ze = *(const float4*)(xb + 2 * hw + rb + ce);
            const float4 me = make_float4((float)mei.x, (float)mei.y,
                                          (float)mei.z, (float)mei.w);
            if (eL) { x0 = xe; y0 = ye; z0 = ze; m0 = me; }
            else    { x2 = xe; y2 = ye; z2 = ze; m2 = me; }
        }

        const float xw[12] = {x0.x,x0.y,x0.z,x0.w, x1.x,x1.y,x1.z,x1.w, x2.x,x2.y,x2.z,x2.w};
        const float yw[12] = {y0.x,y0.y,y0.z,y0.w, y1.x,y1.y,y1.z,y1.w, y2.x,y2.y,y2.z,y2.w};
        const float zw[12] = {z0.x,z0.y,z0.z,z0.w, z1.x,z1.y,z1.z,z1.w, z2.x,z2.y,z2.z,z2.w};
        const float mw[12] = {m0.x,m0.y,m0.z,m0.w, m1.x,m1.y,m1.z,m1.w, m2.x,m2.y,m2.z,m2.w};

        float mf[12];
#pragma unroll
        for (int j = 2; j <= 9; ++j) mf[j] = vf[j] * mw[j];

        // Gaussian weights, once per (pixel, tap), shared across channels.
        float g[PX][5];
#pragma unroll
        for (int i = 0; i < PX; ++i) {
#pragma unroll
            for (int dx = 0; dx < 5; ++dx) {
                const int j = i + dx + 2;
                const float ax = xw[j] - cx[i];
                const float ay = yw[j] - cy[i];
                const float az = zw[j] - cz[i];
                const float d2 = ax * ax + ay * ay + az * az;
                g[i][dx] = mf[j] * __expf(-0.5f * d2);
            }
        }

        // Channel loop: 1 own load + 2 shfls + edge fixup + 20 FMA per channel.
#pragma unroll
        for (int c = 0; c < CPG; ++c) {
            const float* sp = smb + (size_t)c * hw + rb;
            const float4 s1 = *(const float4*)(sp + c1);
            float4 s0 = shflup4(s1), s2 = shfldn4(s1);
            if (eL | eR) {
                const float4 se = *(const float4*)(sp + ce);
                if (eL) s0 = se; else s2 = se;
            }
            const float sw[12] = {s0.x,s0.y,s0.z,s0.w, s1.x,s1.y,s1.z,s1.w, s2.x,s2.y,s2.z,s2.w};
#pragma unroll
            for (int i = 0; i < PX; ++i) {
                float a = acc[c][i];
#pragma unroll
                for (int dx = 0; dx < 5; ++dx)
                    a = fmaf(g[i][dx], sw[i + dx + 2], a);
                acc[c][i] = a;
            }
        }
    }

    float* ob = out + (size_t)n * CC * hw + (size_t)(cg * CPG) * hw + ctr;
#pragma unroll
    for (int c = 0; c < CPG; ++c)
        *(float4*)(ob + (size_t)c * hw) =
            make_float4(acc[c][0], acc[c][1], acc[c][2], acc[c][3]);
}

extern "C" void kernel_launch(void* const* d_in, const int* in_sizes, int n_in,
                              void* d_out, int out_size, void* d_ws, size_t ws_size,
                              hipStream_t stream) {
    const float* xyz     = (const float*)d_in[0];
    const float* softmax = (const float*)d_in[1];
    const int*   mask    = (const int*)d_in[2];
    float*       out     = (float*)d_out;

    dim3 block(256, 1, 1);
    dim3 grid(WW / (PX * 256), HH, NN * CG);   // 2 x 64 x 16 = 2048 blocks
    hipLaunchKernelGGL(lc_xyz_kernel, grid, block, 0, stream,
                       xyz, softmax, mask, out);
}

// Round 14
// 128.361 us; speedup vs baseline: 1.6104x; 1.6104x over previous
//
#include <hip/hip_runtime.h>

#define NN 4
#define CC 20
#define HH 64
#define WW 2048
#define CG 4           // channel groups
#define CPG (CC / CG)  // 5 channels per group
#define PX 4           // pixels per thread

// FINAL (session champion = R4, 127.9us bench, VGPR=60, zero spill).
// 2-chunk unaligned window loads: the 8-tap window [p0-2, p0+5] is two
// dword-aligned float4 loads at p0-2 / p0+2. Edge threads clamp the base
// and repair always-valid center slots 2..5 via cndmask; outer slots
// 0,1,6,7 are zeroed through mf.
// Session post-mortem (13 rounds): every structural transformation of
// this body spilled at the ~64-VGPR cliff (R1/R5/R7/R8/R9/R11) or
// regressed (R2 swizzle: FETCH -50% but dur +10%; R3/R10 occupancy
// floors: allocator forced below natural VGPR -> 3x scratch traffic).
// Kernel is latency-bound at the hard 4-waves/SIMD cap with no pipe
// saturated (HBM 37%, VALU 35%, L1 ~50%); spill-free shapes: R0 and this.
__global__ __launch_bounds__(256, 4) void lc_xyz_kernel(
    const float* __restrict__ xyz,
    const float* __restrict__ softmax,
    const int* __restrict__ mask,
    float* __restrict__ out)
{
    const int t  = blockIdx.x * blockDim.x + threadIdx.x;  // pixel-quad index: 0..511
    const int h  = blockIdx.y;
    const int nz = blockIdx.z;
    const int n  = nz >> 2;
    const int cg = nz & 3;
    const int hw = HH * WW;
    const int p0 = t * PX;

    const float* xb  = xyz     + (size_t)n * 3  * hw;
    const float* smb = softmax + (size_t)n * CC * hw + (size_t)(cg * CPG) * hw;
    const int*   mb  = mask    + (size_t)n * hw;

    const int ctr = h * WW + p0;
    const float4 cxv = *(const float4*)(xb + 0 * hw + ctr);
    const float4 cyv = *(const float4*)(xb + 1 * hw + ctr);
    const float4 czv = *(const float4*)(xb + 2 * hw + ctr);
    const float cx[PX] = {cxv.x, cxv.y, cxv.z, cxv.w};
    const float cy[PX] = {cyv.x, cyv.y, cyv.z, cyv.w};
    const float cz[PX] = {czv.x, czv.y, czv.z, czv.w};

    float acc[CPG][PX];
#pragma unroll
    for (int c = 0; c < CPG; ++c)
#pragma unroll
        for (int i = 0; i < PX; ++i) acc[c][i] = 0.f;

    // Window slot j=0..7 holds position w = p0-2+j; tap (i,dx) uses j=i+dx.
    // Chunk A at a0=p0-2 covers j=0..3, chunk B at b0=p0+2 covers j=4..7.
    // Only the p0==0 thread clamps A (slots 2,3 then come from A.x,A.y);
    // only the p0==WW-4 thread clamps B (slots 4,5 from B.z,B.w).
    const int  a0 = p0 - 2;
    const int  b0 = p0 + 2;
    const bool sl = (a0 < 0);
    const bool sr = (b0 > WW - 4);
    const int  aC = sl ? 0 : a0;
    const int  bC = sr ? (WW - 4) : b0;
    const float vfL = sl ? 0.f : 1.f;   // validity of slots 0,1 (pos p0-2,p0-1)
    const float vfR = sr ? 0.f : 1.f;   // validity of slots 6,7 (pos p0+4,p0+5)

#pragma unroll
    for (int dy = -2; dy <= 2; ++dy) {
        const int row = h + dy;
        if ((unsigned)row >= (unsigned)HH) continue;   // wave-uniform
        const int rb = row * WW;

        // Batched independent row loads: 2 int4 + 6 float4.
        const int4   mA = *(const int4*)(mb + rb + aC);
        const int4   mB = *(const int4*)(mb + rb + bC);
        const float4 xA = *(const float4*)(xb + 0 * hw + rb + aC);
        const float4 xB = *(const float4*)(xb + 0 * hw + rb + bC);
        const float4 yA = *(const float4*)(xb + 1 * hw + rb + aC);
        const float4 yB = *(const float4*)(xb + 1 * hw + rb + bC);
        const float4 zA = *(const float4*)(xb + 2 * hw + rb + aC);
        const float4 zB = *(const float4*)(xb + 2 * hw + rb + bC);

        // Window values; slots 0,1,6,7 may hold clamped garbage (mf zeroes them).
        const float xw[8] = {xA.x, xA.y, sl ? xA.x : xA.z, sl ? xA.y : xA.w,
                             sr ? xB.z : xB.x, sr ? xB.w : xB.y, xB.z, xB.w};
        const float yw[8] = {yA.x, yA.y, sl ? yA.x : yA.z, sl ? yA.y : yA.w,
                             sr ? yB.z : yB.x, sr ? yB.w : yB.y, yB.z, yB.w};
        const float zw[8] = {zA.x, zA.y, sl ? zA.x : zA.z, sl ? zA.y : zA.w,
                             sr ? zB.z : zB.x, sr ? zB.w : zB.y, zB.z, zB.w};

        // Mask window: slots 2..5 are always-valid positions p0..p0+3,
        // slots 0,1 / 6,7 get the validity factor folded in.
        const float mf[8] = {
            vfL * (float)mA.x,
            vfL * (float)mA.y,
            (float)(sl ? mA.x : mA.z),
            (float)(sl ? mA.y : mA.w),
            (float)(sr ? mB.z : mB.x),
            (float)(sr ? mB.w : mB.y),
            vfR * (float)mB.z,
            vfR * (float)mB.w};

        // Gaussian weights, once per (pixel, tap), shared across channels.
        float g[PX][5];
#pragma unroll
        for (int i = 0; i < PX; ++i) {
#pragma unroll
            for (int dx = 0; dx < 5; ++dx) {
                const int j = i + dx;
                const float ax = xw[j] - cx[i];
                const float ay = yw[j] - cy[i];
                const float az = zw[j] - cz[i];
                const float d2 = ax * ax + ay * ay + az * az;
                g[i][dx] = mf[j] * __expf(-0.5f * d2);
            }
        }

        // Channel loop: 2 float4 loads + 20 FMA per channel.
#pragma unroll
        for (int c = 0; c < CPG; ++c) {
            const float* sp = smb + (size_t)c * hw + rb;
            const float4 sA = *(const float4*)(sp + aC);
            const float4 sB = *(const float4*)(sp + bC);
            const float sw[8] = {sA.x, sA.y, sl ? sA.x : sA.z, sl ? sA.y : sA.w,
                                 sr ? sB.z : sB.x, sr ? sB.w : sB.y, sB.z, sB.w};
#pragma unroll
            for (int i = 0; i < PX; ++i) {
                float a = acc[c][i];
#pragma unroll
                for (int dx = 0; dx < 5; ++dx)
                    a = fmaf(g[i][dx], sw[i + dx], a);
                acc[c][i] = a;
            }
        }
    }

    float* ob = out + (size_t)n * CC * hw + (size_t)(cg * CPG) * hw + ctr;
#pragma unroll
    for (int c = 0; c < CPG; ++c)
        *(float4*)(ob + (size_t)c * hw) =
            make_float4(acc[c][0], acc[c][1], acc[c][2], acc[c][3]);
}

extern "C" void kernel_launch(void* const* d_in, const int* in_sizes, int n_in,
                              void* d_out, int out_size, void* d_ws, size_t ws_size,
                              hipStream_t stream) {
    const float* xyz     = (const float*)d_in[0];
    const float* softmax = (const float*)d_in[1];
    const int*   mask    = (const int*)d_in[2];
    float*       out     = (float*)d_out;

    dim3 block(256, 1, 1);
    dim3 grid(WW / (PX * 256), HH, NN * CG);   // 2 x 64 x 16 = 2048 blocks
    hipLaunchKernelGGL(lc_xyz_kernel, grid, block, 0, stream,
                       xyz, softmax, mask, out);
}

// Round 15
// 128.041 us; speedup vs baseline: 1.6145x; 1.0025x over previous
//
#include <hip/hip_runtime.h>

#define NN 4
#define CC 20
#define HH 64
#define WW 2048
#define CG 4           // channel groups
#define CPG (CC / CG)  // 5 channels per group
#define PX 4           // pixels per thread

// R15: EXACT champion body (R4/R14, 128µs bench, VGPR=60, zero spill) with
// ONE change: __launch_bounds__(256,4) -> __launch_bounds__(256).
// Rationale: at VGPR=60 the HW allows 8 waves/SIMD (boundary is 64), yet
// measured occupancy never exceeds ~35% (~10-11 of 32 waves/CU). The
// 2nd launch_bounds arg emits amdgpu-waves-per-eu=4 which may act as an
// occupancy CAP at 16 waves/CU (time-averaged ~32% = exactly what we see).
// R3/(256,8) and R10/(256,6) could not test this: they moved the VGPR
// budget simultaneously and spilled. Dropping the arg keeps the natural
// 60-reg allocation (no budget floor) and lets residency float to the
// VGPR-determined limit.
// Tripwires: VGPR must stay 56-64, WRITE_SIZE must stay 40960 KB; any
// deviation -> revert to R14 verbatim and close the session.
__global__ __launch_bounds__(256) void lc_xyz_kernel(
    const float* __restrict__ xyz,
    const float* __restrict__ softmax,
    const int* __restrict__ mask,
    float* __restrict__ out)
{
    const int t  = blockIdx.x * blockDim.x + threadIdx.x;  // pixel-quad index: 0..511
    const int h  = blockIdx.y;
    const int nz = blockIdx.z;
    const int n  = nz >> 2;
    const int cg = nz & 3;
    const int hw = HH * WW;
    const int p0 = t * PX;

    const float* xb  = xyz     + (size_t)n * 3  * hw;
    const float* smb = softmax + (size_t)n * CC * hw + (size_t)(cg * CPG) * hw;
    const int*   mb  = mask    + (size_t)n * hw;

    const int ctr = h * WW + p0;
    const float4 cxv = *(const float4*)(xb + 0 * hw + ctr);
    const float4 cyv = *(const float4*)(xb + 1 * hw + ctr);
    const float4 czv = *(const float4*)(xb + 2 * hw + ctr);
    const float cx[PX] = {cxv.x, cxv.y, cxv.z, cxv.w};
    const float cy[PX] = {cyv.x, cyv.y, cyv.z, cyv.w};
    const float cz[PX] = {czv.x, czv.y, czv.z, czv.w};

    float acc[CPG][PX];
#pragma unroll
    for (int c = 0; c < CPG; ++c)
#pragma unroll
        for (int i = 0; i < PX; ++i) acc[c][i] = 0.f;

    // Window slot j=0..7 holds position w = p0-2+j; tap (i,dx) uses j=i+dx.
    // Chunk A at a0=p0-2 covers j=0..3, chunk B at b0=p0+2 covers j=4..7.
    // Only the p0==0 thread clamps A (slots 2,3 then come from A.x,A.y);
    // only the p0==WW-4 thread clamps B (slots 4,5 from B.z,B.w).
    const int  a0 = p0 - 2;
    const int  b0 = p0 + 2;
    const bool sl = (a0 < 0);
    const bool sr = (b0 > WW - 4);
    const int  aC = sl ? 0 : a0;
    const int  bC = sr ? (WW - 4) : b0;
    const float vfL = sl ? 0.f : 1.f;   // validity of slots 0,1 (pos p0-2,p0-1)
    const float vfR = sr ? 0.f : 1.f;   // validity of slots 6,7 (pos p0+4,p0+5)

#pragma unroll
    for (int dy = -2; dy <= 2; ++dy) {
        const int row = h + dy;
        if ((unsigned)row >= (unsigned)HH) continue;   // wave-uniform
        const int rb = row * WW;

        // Batched independent row loads: 2 int4 + 6 float4.
        const int4   mA = *(const int4*)(mb + rb + aC);
        const int4   mB = *(const int4*)(mb + rb + bC);
        const float4 xA = *(const float4*)(xb + 0 * hw + rb + aC);
        const float4 xB = *(const float4*)(xb + 0 * hw + rb + bC);
        const float4 yA = *(const float4*)(xb + 1 * hw + rb + aC);
        const float4 yB = *(const float4*)(xb + 1 * hw + rb + bC);
        const float4 zA = *(const float4*)(xb + 2 * hw + rb + aC);
        const float4 zB = *(const float4*)(xb + 2 * hw + rb + bC);

        // Window values; slots 0,1,6,7 may hold clamped garbage (mf zeroes them).
        const float xw[8] = {xA.x, xA.y, sl ? xA.x : xA.z, sl ? xA.y : xA.w,
                             sr ? xB.z : xB.x, sr ? xB.w : xB.y, xB.z, xB.w};
        const float yw[8] = {yA.x, yA.y, sl ? yA.x : yA.z, sl ? yA.y : yA.w,
                             sr ? yB.z : yB.x, sr ? yB.w : yB.y, yB.z, yB.w};
        const float zw[8] = {zA.x, zA.y, sl ? zA.x : zA.z, sl ? zA.y : zA.w,
                             sr ? zB.z : zB.x, sr ? zB.w : zB.y, zB.z, zB.w};

        // Mask window: slots 2..5 are always-valid positions p0..p0+3,
        // slots 0,1 / 6,7 get the validity factor folded in.
        const float mf[8] = {
            vfL * (float)mA.x,
            vfL * (float)mA.y,
            (float)(sl ? mA.x : mA.z),
            (float)(sl ? mA.y : mA.w),
            (float)(sr ? mB.z : mB.x),
            (float)(sr ? mB.w : mB.y),
            vfR * (float)mB.z,
            vfR * (float)mB.w};

        // Gaussian weights, once per (pixel, tap), shared across channels.
        float g[PX][5];
#pragma unroll
        for (int i = 0; i < PX; ++i) {
#pragma unroll
            for (int dx = 0; dx < 5; ++dx) {
                const int j = i + dx;
                const float ax = xw[j] - cx[i];
                const float ay = yw[j] - cy[i];
                const float az = zw[j] - cz[i];
                const float d2 = ax * ax + ay * ay + az * az;
                g[i][dx] = mf[j] * __expf(-0.5f * d2);
            }
        }

        // Channel loop: 2 float4 loads + 20 FMA per channel.
#pragma unroll
        for (int c = 0; c < CPG; ++c) {
            const float* sp = smb + (size_t)c * hw + rb;
            const float4 sA = *(const float4*)(sp + aC);
            const float4 sB = *(const float4*)(sp + bC);
            const float sw[8] = {sA.x, sA.y, sl ? sA.x : sA.z, sl ? sA.y : sA.w,
                                 sr ? sB.z : sB.x, sr ? sB.w : sB.y, sB.z, sB.w};
#pragma unroll
            for (int i = 0; i < PX; ++i) {
                float a = acc[c][i];
#pragma unroll
                for (int dx = 0; dx < 5; ++dx)
                    a = fmaf(g[i][dx], sw[i + dx], a);
                acc[c][i] = a;
            }
        }
    }

    float* ob = out + (size_t)n * CC * hw + (size_t)(cg * CPG) * hw + ctr;
#pragma unroll
    for (int c = 0; c < CPG; ++c)
        *(float4*)(ob + (size_t)c * hw) =
            make_float4(acc[c][0], acc[c][1], acc[c][2], acc[c][3]);
}

extern "C" void kernel_launch(void* const* d_in, const int* in_sizes, int n_in,
                              void* d_out, int out_size, void* d_ws, size_t ws_size,
                              hipStream_t stream) {
    const float* xyz     = (const float*)d_in[0];
    const float* softmax = (const float*)d_in[1];
    const int*   mask    = (const int*)d_in[2];
    float*       out     = (float*)d_out;

    dim3 block(256, 1, 1);
    dim3 grid(WW / (PX * 256), HH, NN * CG);   // 2 x 64 x 16 = 2048 blocks
    hipLaunchKernelGGL(lc_xyz_kernel, grid, block, 0, stream,
                       xyz, softmax, mask, out);
}